// Round 2
// baseline (117.320 us; speedup 1.0000x reference)
//
#include <hip/hip_runtime.h>

// N_RNA=20000, N_PROT=5000, D=128, C=4, E=500000
#define DIM 128
#define NCLS 4
#define NXCD 8

typedef _Float16 f16x4 __attribute__((ext_vector_type(4)));
typedef _Float16 f16x8 __attribute__((ext_vector_type(8)));
typedef float    f32x4 __attribute__((ext_vector_type(4)));

// ---------- merged fp32 -> fp16 conversion (both tables) + zero bin counters ----------
__global__ __launch_bounds__(256) void cvt_both_kernel(
    const float* __restrict__ s1, _Float16* __restrict__ d1, int n1,
    const float* __restrict__ s2, _Float16* __restrict__ d2, int n2,
    int* __restrict__ counters)   // may be null; 8 bucket counters to zero
{
    if (counters && blockIdx.x == 0 && threadIdx.x < NXCD) counters[threadIdx.x] = 0;
    // n1, n2 are multiples of 8, so an 8-group never straddles the boundary.
    const int total = n1 + n2;
    int i = (blockIdx.x * blockDim.x + threadIdx.x) * 8;
    const int stride = gridDim.x * blockDim.x * 8;
    for (; i < total; i += stride) {
        const float* s; _Float16* d; int j;
        if (i < n1) { s = s1; d = d1; j = i; }
        else        { s = s2; d = d2; j = i - n1; }
        const float4 a = *(const float4*)(s + j);
        const float4 b = *(const float4*)(s + j + 4);
        f16x8 o;
        o[0] = (_Float16)a.x; o[1] = (_Float16)a.y;
        o[2] = (_Float16)a.z; o[3] = (_Float16)a.w;
        o[4] = (_Float16)b.x; o[5] = (_Float16)b.y;
        o[6] = (_Float16)b.z; o[7] = (_Float16)b.w;
        *(f16x8*)(d + j) = o;
    }
}

// ---------- bin edges into 8 buckets by RNA-row slice (XCD L2 locality) ----------
// Entry: int4{ e, ri, pi, 0 } appended to region[bucket]; block-aggregated atomics:
// 8 global atomicAdds per block (Guideline 12), per-edge appends via LDS cursors.
#define BIN_EPT 4   // edges per thread
__global__ __launch_bounds__(256) void bin_edges_kernel(
    const int* __restrict__ ridx, const int* __restrict__ pidx, int nEdges,
    int rowsPerBucket, int4* __restrict__ entries, size_t bucketStride /*entries*/,
    int* __restrict__ counters)
{
    __shared__ int lds_count[NXCD];
    __shared__ int lds_base[NXCD];
    __shared__ int lds_cur[NXCD];
    if (threadIdx.x < NXCD) { lds_count[threadIdx.x] = 0; lds_cur[threadIdx.x] = 0; }
    __syncthreads();

    const int blockStart = blockIdx.x * (256 * BIN_EPT);
    int e[BIN_EPT], ri[BIN_EPT], pi[BIN_EPT], bk[BIN_EPT];
#pragma unroll
    for (int k = 0; k < BIN_EPT; ++k) {
        const int ee = blockStart + threadIdx.x + k * 256;   // coalesced
        e[k] = ee;
        if (ee < nEdges) {
            ri[k] = ridx[ee];
            pi[k] = pidx[ee];
            bk[k] = ri[k] / rowsPerBucket;
            atomicAdd(&lds_count[bk[k]], 1);
        }
    }
    __syncthreads();
    if (threadIdx.x < NXCD) {
        const int c = lds_count[threadIdx.x];
        lds_base[threadIdx.x] = c ? atomicAdd(&counters[threadIdx.x], c) : 0;
    }
    __syncthreads();
#pragma unroll
    for (int k = 0; k < BIN_EPT; ++k) {
        if (e[k] < nEdges) {
            const int b   = bk[k];
            const int pos = lds_base[b] + atomicAdd(&lds_cur[b], 1);
            int4 ent; ent.x = e[k]; ent.y = ri[k]; ent.z = pi[k]; ent.w = 0;
            entries[(size_t)b * bucketStride + pos] = ent;
        }
    }
}

// ---------- MFMA decoder over XCD-pinned buckets ----------
// out[e, 0:4] = relu( (r[e] .* p[e]) @ WF ), WF[d, c] = sum_cc wrel[cc,d]*wcls[cc*4+c]
// One v_mfma_f32_16x16x32_f16 = 16 edges x 4 classes x K=32; 4 chained MFMAs = D=128.
//   A = WF^T (rows 0..3 = classes, 4..15 zero), B = q = r.*p (col = edge).
//   D layout col=lane&15, row=(lane>>4)*4+reg: lanes 0..15 hold float4 of classes.
// Block bid serves bucket bid&7 (== XCD via round-robin dispatch heuristic), so this
// block's RNA gathers stay inside a 640KB slice resident in that XCD's 4MB L2.
__global__ __launch_bounds__(256, 4) void decoder_mfma_binned_kernel(
    const _Float16* __restrict__ rna,   // [N_RNA, D] f16
    const _Float16* __restrict__ prot,  // [N_PROT, D] f16
    const int4*  __restrict__ entries, size_t bucketStride /*entries*/,
    const int*   __restrict__ counters,
    const float* __restrict__ wrel,
    const float* __restrict__ wcls,
    float*       __restrict__ out)
{
    // ---- fused f16 weights in LDS: wf_lds[c][d] = sum_cc wrel[cc,d]*wcls[cc,c]
    __shared__ _Float16 wf_lds[NCLS][DIM];
    {
        const int t = threadIdx.x;
        if (t < DIM) {
            const float w0 = wrel[0 * DIM + t];
            const float w1 = wrel[1 * DIM + t];
            const float w2 = wrel[2 * DIM + t];
            const float w3 = wrel[3 * DIM + t];
#pragma unroll
            for (int c = 0; c < NCLS; ++c) {
                wf_lds[c][t] = (_Float16)(w0 * wcls[0 * 4 + c] + w1 * wcls[1 * 4 + c] +
                                          w2 * wcls[2 * 4 + c] + w3 * wcls[3 * 4 + c]);
            }
        }
    }
    __syncthreads();

    const int lane = threadIdx.x & 63;
    const int l16  = lane & 15;   // edge-in-group (B cols) / class row (A)
    const int kg   = lane >> 4;   // k-subgroup 0..3 (8 f16 each)

    f16x8 awf[4];
    const f16x8 fzero = {};
#pragma unroll
    for (int f = 0; f < 4; ++f)
        awf[f] = (l16 < NCLS) ? *(const f16x8*)(&wf_lds[l16][f * 32 + kg * 8]) : fzero;

    const int bucket = blockIdx.x & (NXCD - 1);
    const int sub    = blockIdx.x >> 3;
    const int nsub   = gridDim.x >> 3;
    const int nb     = counters[bucket];
    const int4* bent = entries + (size_t)bucket * bucketStride;

    const int wInB  = sub * (blockDim.x >> 6) + (threadIdx.x >> 6);
    const int nwInB = nsub * (blockDim.x >> 6);

    const size_t khi  = (size_t)kg * 16;    // byte offset of k-subgroup in 256B row
    const char* rbase = (const char*)rna  + khi;
    const char* pbase = (const char*)prot + khi;

    for (int g = wInB * 32; g < nb; g += nwInB * 32) {
        const int iA = g + l16, iB = g + 16 + l16;
        int4 eA, eB;
        if (iA < nb) eA = bent[iA]; else { eA.x = -1; eA.y = 0; eA.z = 0; }
        if (iB < nb) eB = bent[iB]; else { eB.x = -1; eB.y = 0; eB.z = 0; }

        // ---- issue all 16 gather dwordx4 loads back-to-back ----
        const char* ra = rbase + ((size_t)eA.y << 8);
        const char* pa = pbase + ((size_t)eA.z << 8);
        const char* rb = rbase + ((size_t)eB.y << 8);
        const char* pb = pbase + ((size_t)eB.z << 8);
        f16x8 rAv[4], pAv[4], rBv[4], pBv[4];
#pragma unroll
        for (int f = 0; f < 4; ++f) rAv[f] = *(const f16x8*)(ra + f * 64);
#pragma unroll
        for (int f = 0; f < 4; ++f) pAv[f] = *(const f16x8*)(pa + f * 64);
#pragma unroll
        for (int f = 0; f < 4; ++f) rBv[f] = *(const f16x8*)(rb + f * 64);
#pragma unroll
        for (int f = 0; f < 4; ++f) pBv[f] = *(const f16x8*)(pb + f * 64);

        // ---- q = r .* p (packed f16), reduce via MFMA ----
        f32x4 accA = {}, accB = {};
#pragma unroll
        for (int f = 0; f < 4; ++f) {
            const f16x8 q = rAv[f] * pAv[f];
            accA = __builtin_amdgcn_mfma_f32_16x16x32_f16(awf[f], q, accA, 0, 0, 0);
        }
#pragma unroll
        for (int f = 0; f < 4; ++f) {
            const f16x8 q = rBv[f] * pBv[f];
            accB = __builtin_amdgcn_mfma_f32_16x16x32_f16(awf[f], q, accB, 0, 0, 0);
        }

        // ---- relu + float4 store to original edge position ----
        if (lane < 16) {
            if (eA.x >= 0) {
                f32x4 oA;
#pragma unroll
                for (int j = 0; j < 4; ++j) oA[j] = fmaxf(accA[j], 0.0f);
                *(f32x4*)(out + (size_t)eA.x * NCLS) = oA;
            }
            if (eB.x >= 0) {
                f32x4 oB;
#pragma unroll
                for (int j = 0; j < 4; ++j) oB[j] = fmaxf(accB[j], 0.0f);
                *(f32x4*)(out + (size_t)eB.x * NCLS) = oB;
            }
        }
    }
}

// ---------- non-binned MFMA decoder (middle fallback, verified in R1) ----------
__global__ __launch_bounds__(256, 4) void decoder_mfma_kernel(
    const _Float16* __restrict__ rna, const _Float16* __restrict__ prot,
    const int* __restrict__ ridx, const int* __restrict__ pidx,
    const float* __restrict__ wrel, const float* __restrict__ wcls,
    float* __restrict__ out, int nEdges)   // requires nEdges % 32 == 0
{
    __shared__ _Float16 wf_lds[NCLS][DIM];
    {
        const int t = threadIdx.x;
        if (t < DIM) {
            const float w0 = wrel[0 * DIM + t];
            const float w1 = wrel[1 * DIM + t];
            const float w2 = wrel[2 * DIM + t];
            const float w3 = wrel[3 * DIM + t];
#pragma unroll
            for (int c = 0; c < NCLS; ++c) {
                wf_lds[c][t] = (_Float16)(w0 * wcls[0 * 4 + c] + w1 * wcls[1 * 4 + c] +
                                          w2 * wcls[2 * 4 + c] + w3 * wcls[3 * 4 + c]);
            }
        }
    }
    __syncthreads();

    const int lane = threadIdx.x & 63;
    const int l16  = lane & 15;
    const int kg   = lane >> 4;

    f16x8 awf[4];
    const f16x8 fzero = {};
#pragma unroll
    for (int f = 0; f < 4; ++f)
        awf[f] = (l16 < NCLS) ? *(const f16x8*)(&wf_lds[l16][f * 32 + kg * 8]) : fzero;

    const int wid   = (int)((blockIdx.x * blockDim.x + threadIdx.x) >> 6);
    const int nw    = (int)((gridDim.x * blockDim.x) >> 6);
    const int npair = nEdges >> 5;

    const size_t khi  = (size_t)kg * 16;
    const char* rbase = (const char*)rna  + khi;
    const char* pbase = (const char*)prot + khi;

    int pr = wid;
    if (pr >= npair) return;
    int e0  = pr * 32;
    int riA = ridx[e0 + l16],      piA = pidx[e0 + l16];
    int riB = ridx[e0 + 16 + l16], piB = pidx[e0 + 16 + l16];

    for (;;) {
        const char* ra = rbase + ((size_t)riA << 8);
        const char* pa = pbase + ((size_t)piA << 8);
        const char* rb = rbase + ((size_t)riB << 8);
        const char* pb = pbase + ((size_t)piB << 8);
        f16x8 rAv[4], pAv[4], rBv[4], pBv[4];
#pragma unroll
        for (int f = 0; f < 4; ++f) rAv[f] = *(const f16x8*)(ra + f * 64);
#pragma unroll
        for (int f = 0; f < 4; ++f) pAv[f] = *(const f16x8*)(pa + f * 64);
#pragma unroll
        for (int f = 0; f < 4; ++f) rBv[f] = *(const f16x8*)(rb + f * 64);
#pragma unroll
        for (int f = 0; f < 4; ++f) pBv[f] = *(const f16x8*)(pb + f * 64);

        const int  prn  = pr + nw;
        const bool more = prn < npair;
        if (more) {
            const int en = prn * 32;
            riA = ridx[en + l16];      piA = pidx[en + l16];
            riB = ridx[en + 16 + l16]; piB = pidx[en + 16 + l16];
        }

        f32x4 accA = {}, accB = {};
#pragma unroll
        for (int f = 0; f < 4; ++f) {
            const f16x8 q = rAv[f] * pAv[f];
            accA = __builtin_amdgcn_mfma_f32_16x16x32_f16(awf[f], q, accA, 0, 0, 0);
        }
#pragma unroll
        for (int f = 0; f < 4; ++f) {
            const f16x8 q = rBv[f] * pBv[f];
            accB = __builtin_amdgcn_mfma_f32_16x16x32_f16(awf[f], q, accB, 0, 0, 0);
        }

        if (lane < 16) {
            f32x4 oA, oB;
#pragma unroll
            for (int j = 0; j < 4; ++j) {
                oA[j] = fmaxf(accA[j], 0.0f);
                oB[j] = fmaxf(accB[j], 0.0f);
            }
            *(f32x4*)(out + (size_t)(e0 + l16) * NCLS)      = oA;
            *(f32x4*)(out + (size_t)(e0 + 16 + l16) * NCLS) = oB;
        }

        if (!more) break;
        pr = prn;
        e0 = prn * 32;
    }
}

// ---------- fp32 fallback (handles any shape / tiny workspace) ----------
__device__ __forceinline__ float reduce4_f32(float b0, float b1, float b2, float b3, int lane)
{
    const bool lo1 = (lane & 1) == 0;
    float k0 = lo1 ? b0 : b2, s0 = lo1 ? b2 : b0;
    float k1 = lo1 ? b1 : b3, s1 = lo1 ? b3 : b1;
    float v0 = k0 + __shfl_xor(s0, 1, 32);
    float v1 = k1 + __shfl_xor(s1, 1, 32);
    const bool lo2 = (lane & 2) == 0;
    float k = lo2 ? v0 : v1, s = lo2 ? v1 : v0;
    float v = k + __shfl_xor(s, 2, 32);
    v += __shfl_xor(v, 4, 32);
    v += __shfl_xor(v, 8, 32);
    v += __shfl_xor(v, 16, 32);
    return v;
}

__global__ __launch_bounds__(256) void decoder_f32_kernel(
    const float* __restrict__ rna, const float* __restrict__ prot,
    const int* __restrict__ ridx, const int* __restrict__ pidx,
    const float* __restrict__ wrel, const float* __restrict__ wcls,
    float* __restrict__ out, int nEdges)
{
    const int lane32 = threadIdx.x & 31;
    const int hw     = (blockIdx.x * blockDim.x + threadIdx.x) >> 5;
    const int nhw    = (gridDim.x * blockDim.x) >> 5;
    const float4 w0 = *(const float4*)(wrel + 0 * DIM + lane32 * 4);
    const float4 w1 = *(const float4*)(wrel + 1 * DIM + lane32 * 4);
    const float4 w2 = *(const float4*)(wrel + 2 * DIM + lane32 * 4);
    const float4 w3 = *(const float4*)(wrel + 3 * DIM + lane32 * 4);
    float wc[16];
#pragma unroll
    for (int i = 0; i < 16; ++i) wc[i] = wcls[i];
    float4 wf[4];
#pragma unroll
    for (int j = 0; j < 4; ++j) {
        wf[j].x = wc[j] * w0.x + wc[4 + j] * w1.x + wc[8 + j] * w2.x + wc[12 + j] * w3.x;
        wf[j].y = wc[j] * w0.y + wc[4 + j] * w1.y + wc[8 + j] * w2.y + wc[12 + j] * w3.y;
        wf[j].z = wc[j] * w0.z + wc[4 + j] * w1.z + wc[8 + j] * w2.z + wc[12 + j] * w3.z;
        wf[j].w = wc[j] * w0.w + wc[4 + j] * w1.w + wc[8 + j] * w2.w + wc[12 + j] * w3.w;
    }
    const int cls   = ((lane32 & 1) << 1) | ((lane32 >> 1) & 1);
    const int lelem = lane32 * 4;
    for (int e = hw; e < nEdges; e += nhw) {
        const float4 r = *(const float4*)(rna  + (size_t)ridx[e] * DIM + lelem);
        const float4 p = *(const float4*)(prot + (size_t)pidx[e] * DIM + lelem);
        float qx = r.x * p.x, qy = r.y * p.y, qz = r.z * p.z, qw = r.w * p.w;
        float b0 = qx * wf[0].x + qy * wf[0].y + qz * wf[0].z + qw * wf[0].w;
        float b1 = qx * wf[1].x + qy * wf[1].y + qz * wf[1].z + qw * wf[1].w;
        float b2 = qx * wf[2].x + qy * wf[2].y + qz * wf[2].z + qw * wf[2].w;
        float b3 = qx * wf[3].x + qy * wf[3].y + qz * wf[3].z + qw * wf[3].w;
        const float v = reduce4_f32(b0, b1, b2, b3, lane32);
        if (lane32 < 4) out[(size_t)e * NCLS + cls] = fmaxf(v, 0.0f);
    }
}

extern "C" void kernel_launch(void* const* d_in, const int* in_sizes, int n_in,
                              void* d_out, int out_size, void* d_ws, size_t ws_size,
                              hipStream_t stream) {
    const float* rna  = (const float*)d_in[0];
    const float* prot = (const float*)d_in[1];
    const int*   ridx = (const int*)d_in[2];
    const int*   pidx = (const int*)d_in[3];
    const float* wrel = (const float*)d_in[4];
    const float* wcls = (const float*)d_in[5];
    float*       out  = (float*)d_out;

    const int nRnaElems  = in_sizes[0];   // 20000*128
    const int nProtElems = in_sizes[1];   // 5000*128
    const int nEdges     = in_sizes[2];   // 500000
    const int nRna       = nRnaElems / DIM;

    const size_t rnaBytes  = (size_t)nRnaElems * 2;
    const size_t protBytes = (size_t)nProtElems * 2;
    size_t off = (rnaBytes + protBytes + 255) & ~(size_t)255;
    const size_t cntOff = off;               // 8 int counters (256B slot)
    const size_t binOff = off + 256;
    const size_t binBytes = (size_t)NXCD * (size_t)nEdges * sizeof(int4);
    const size_t needBinned = binOff + binBytes;
    const size_t needTables = rnaBytes + protBytes;

    const bool tablesOk = (nRnaElems % 8) == 0 && (nProtElems % 8) == 0 && nRna > 0;

    if (tablesOk && ws_size >= needBinned && nEdges >= 1) {
        _Float16* rnaH  = (_Float16*)d_ws;
        _Float16* protH = (_Float16*)((char*)d_ws + rnaBytes);
        int*      cnt   = (int*)((char*)d_ws + cntOff);
        int4*     ents  = (int4*)((char*)d_ws + binOff);
        const size_t bucketStride = (size_t)nEdges;   // entries per bucket region
        const int rowsPerBucket = (nRna + NXCD - 1) / NXCD;

        const int totalElems = nRnaElems + nProtElems;
        const int cvtBlocks  = (totalElems / 8 + 255) / 256;
        hipLaunchKernelGGL(cvt_both_kernel, dim3(cvtBlocks), dim3(256), 0, stream,
                           rna, rnaH, nRnaElems, prot, protH, nProtElems, cnt);

        const int binBlocks = (nEdges + 256 * BIN_EPT - 1) / (256 * BIN_EPT);
        hipLaunchKernelGGL(bin_edges_kernel, dim3(binBlocks), dim3(256), 0, stream,
                           ridx, pidx, nEdges, rowsPerBucket, ents, bucketStride, cnt);

        // 2048 blocks: 256 sub-blocks per bucket; bucket = blockIdx&7 pins each
        // bucket's RNA slice (640KB f16) + full prot table (1.28MB) into one XCD L2.
        hipLaunchKernelGGL(decoder_mfma_binned_kernel, dim3(2048), dim3(256), 0, stream,
                           rnaH, protH, ents, bucketStride, cnt, wrel, wcls, out);
    } else if (tablesOk && ws_size >= needTables && (nEdges % 32) == 0 && nEdges >= 32) {
        _Float16* rnaH  = (_Float16*)d_ws;
        _Float16* protH = (_Float16*)((char*)d_ws + rnaBytes);
        const int totalElems = nRnaElems + nProtElems;
        const int cvtBlocks  = (totalElems / 8 + 255) / 256;
        hipLaunchKernelGGL(cvt_both_kernel, dim3(cvtBlocks), dim3(256), 0, stream,
                           rna, rnaH, nRnaElems, prot, protH, nProtElems, (int*)nullptr);
        hipLaunchKernelGGL(decoder_mfma_kernel, dim3(1024), dim3(256), 0, stream,
                           rnaH, protH, ridx, pidx, wrel, wcls, out, nEdges);
    } else {
        hipLaunchKernelGGL(decoder_f32_kernel, dim3(8192), dim3(256), 0, stream,
                           rna, prot, ridx, pidx, wrel, wcls, out, nEdges);
    }
}